// Round 3
// baseline (227.325 us; speedup 1.0000x reference)
//
#include <hip/hip_runtime.h>
#include <hip/hip_bf16.h>

typedef unsigned short ushort_t;

#define N_IMG 32
#define C_IN  128
#define C_OUT 256
#define H_SZ  56
#define W_SZ  56
#define HW_SZ (H_SZ * W_SZ)        // 3136
#define K_TOT (C_IN * 9)           // 1152
#define WP 64                      // padded width  (w' = w+1, zeros at 0,57..63)
#define HP 58                      // padded height (h1 = h+1, zeros at 0,57)
#define ROW_E (WP * C_IN)          // 8192 elements per padded (n,h1) slab

typedef __attribute__((ext_vector_type(8))) short bf16x8;
typedef __attribute__((ext_vector_type(4))) float floatx4;

__device__ __forceinline__ void gl_lds16(const ushort_t* g, ushort_t* l) {
  __builtin_amdgcn_global_load_lds(
      (const __attribute__((address_space(1))) void*)g,
      (__attribute__((address_space(3))) void*)l, 16, 0, 0);
}

__device__ __forceinline__ ushort_t f2bf(float f) {
  __hip_bfloat16 b = __float2bfloat16(f);
  return *reinterpret_cast<ushort_t*>(&b);
}

// w_q (int32 {-1,0,1}, [co][c][kh][kw]) -> w_t bf16 [co][tap*128+c]
__global__ void wtrans_kernel(const int* __restrict__ wq, ushort_t* __restrict__ wt) {
  int idx = blockIdx.x * 256 + threadIdx.x;
  if (idx >= C_OUT * K_TOT) return;
  int co = idx / K_TOT;
  int k  = idx - co * K_TOT;
  int tap = k >> 7;
  int c   = k & 127;
  int kh = tap / 3, kw = tap - kh * 3;
  int v = wq[((co * C_IN + c) * 3 + kh) * 3 + kw];
  wt[idx] = f2bf((float)v);
}

// x fp32 NCHW -> xp bf16 padded-NHWC: xp[n][h1][w'][c], h1=h+1 (0,57 zero),
// w'=w+1 (0,57..63 zero), +1 slack row at the end (OOB spill for discarded cols).
__global__ __launch_bounds__(256) void xpad_kernel(const float* __restrict__ x,
                                                   ushort_t* __restrict__ xp) {
  int b = blockIdx.x;                 // 0..N_IMG*HP (last = slack row)
  int t = threadIdx.x;
  ushort_t* row = xp + (size_t)b * ROW_E;
  int n = b / HP;
  int h1 = b - n * HP;
  if (b >= N_IMG * HP || h1 == 0 || h1 == HP - 1) {
    uint4 z = {0u, 0u, 0u, 0u};
    uint4* r4 = (uint4*)row;          // 16384 B = 1024 uint4
#pragma unroll
    for (int i = 0; i < 4; ++i) r4[i * 256 + t] = z;
    return;
  }
  __shared__ float tile[C_IN * 57];   // stride 57: store-phase 4-way max (free-ish)
  int h = h1 - 1;
  const float* xb = x + (size_t)n * C_IN * HW_SZ + h * W_SZ;
#pragma unroll
  for (int i = 0; i < 7; ++i) {
    int idx = i * 256 + t;            // 0..1791 = 128 c * 14 float4
    int c = idx / 14, f = idx - c * 14;
    float4 v = *(const float4*)(xb + (size_t)c * HW_SZ + f * 4);
    float* dst = &tile[c * 57 + f * 4];
    dst[0] = v.x; dst[1] = v.y; dst[2] = v.z; dst[3] = v.w;
  }
  __syncthreads();
  unsigned int* r32 = (unsigned int*)row;
#pragma unroll
  for (int i = 0; i < 16; ++i) {
    int idx = i * 256 + t;            // 0..4095 = 64 w' * 64 cpair
    int wp = idx >> 6, cp = idx & 63;
    unsigned int u = 0;
    if (wp >= 1 && wp <= W_SZ) {
      int w = wp - 1;
      u = (unsigned int)f2bf(tile[(2 * cp) * 57 + w]) |
          ((unsigned int)f2bf(tile[(2 * cp + 1) * 57 + w]) << 16);
    }
    r32[wp * 64 + cp] = u;            // 256 B contiguous per w'
  }
}

// Implicit GEMM, BK=32, 3-buffer ring, ONE barrier per step, depth-2 prefetch.
// Per iter st: vmcnt(4) [step st's 4 loads, issued at iter st-2, landed] ->
// s_barrier [everyone's landed; also everyone's st-1 reads done] ->
// stage(st+2 -> buf[(st+2)%3]) [overwrites buf last read at st-1: safe, the
// barrier postdates those reads] -> 8 ds_read_b128 + 16 MFMA from buf[st%3].
// vmcnt never drains to 0 in the main loop; loads live across 2 barriers.
// LDS 48 KB (3 x (8+8) KB) -> 3 blocks/CU LDS-wise (was 2 at 64 KB).
// Swizzle (64B rows, 4 chunks of 16B): slot = chunk ^ ((row>>1)&3);
// staging pre-swizzles the GLOBAL address: lane fetches chunk
// (lane&3)^((lane>>3)&3) so the linear gl_lds dest lands swizzled; reads
// spread 16-lane groups 2-per-bank (free, m136).
__global__ __launch_bounds__(256) void bitconv_kernel(
    const ushort_t* __restrict__ wt, const ushort_t* __restrict__ xp,
    const float* __restrict__ s, const float* __restrict__ bias,
    float* __restrict__ out) {
  __shared__ ushort_t As[3][128 * 32];   // 3 x 8 KB [co_local][k 32]
  __shared__ ushort_t Bs[3][128 * 32];   // 3 x 8 KB [sp_local][k 32]

  // XCD swizzle: XCD = d&7 gets contiguous sp range (xp slice ~3.8MB -> L2);
  // co-pair of one sp tile adjacent in dispatch on the same XCD.
  int d = blockIdx.x;                 // 1792 = 8 XCD * 2 co * 112 sp
  int xcd = d & 7;
  int r   = d >> 3;                   // 0..223
  int co0 = (r & 1) * 128;
  int sp_tile = xcd * 112 + (r >> 1); // 0..895
  int nh0 = sp_tile * 2;
  int n  = nh0 / H_SZ;
  int hh = nh0 - n * H_SZ;            // even; tile rows hh, hh+1

  int tid  = threadIdx.x;
  int lane = tid & 63;
  int wid  = tid >> 6;
  int l15  = lane & 15;
  int quad = lane >> 4;
  int wave_m = (wid >> 1) * 64;
  int wave_n = (wid & 1) * 64;

  // Staging: wave wid owns rows [wid*32, wid*32+32), 2 groups of 16 rows.
  // Per-lane: row = g*16 + (lane>>2), fetched chunk q = (lane&3)^((lane>>3)&3).
  int qoff = (((lane & 3) ^ ((lane >> 3) & 3)) * 8);  // element offset of 16B chunk
  const ushort_t* a_src[2];
  const ushort_t* b_src[2];
  int dst_e[2];
#pragma unroll
  for (int g = 0; g < 2; ++g) {
    int rrow = wid * 32 + g * 16 + (lane >> 2);   // 0..127
    a_src[g] = wt + (size_t)(co0 + rrow) * K_TOT + qoff;
    int hrow = rrow >> 6, wpp = (rrow & 63) + 1;
    b_src[g] = xp + (size_t)((n * HP + hh + 1 + hrow) * WP + wpp) * C_IN + qoff;
    dst_e[g] = (wid * 32 + g * 16) * 32;
  }

  // Read-side swizzled chunk offset (elements): chunk = quad (0..3),
  // slot = quad ^ ((row>>1)&3), row bits from l15.
  int koff = (quad ^ ((l15 >> 1) & 3)) * 8;

  floatx4 acc[4][4];
#pragma unroll
  for (int mi = 0; mi < 4; ++mi)
#pragma unroll
    for (int ni = 0; ni < 4; ++ni)
      acc[mi][ni] = (floatx4){0.f, 0.f, 0.f, 0.f};

  // stage step st (tap = st>>2, k-quarter = st&3) into buffer buf —
  // all offsets compile-time after full unroll.
  auto stage = [&](int st, int buf) {
    int tap = st >> 2;
    int q32 = st & 3;
    int aoff = tap * C_IN + q32 * 32;
    int boff = (tap / 3 - 1) * ROW_E + (tap % 3 - 1) * C_IN + q32 * 32;
#pragma unroll
    for (int g = 0; g < 2; ++g) {
      gl_lds16(a_src[g] + aoff, &As[buf][dst_e[g]]);
      gl_lds16(b_src[g] + boff, &Bs[buf][dst_e[g]]);
    }
  };

  stage(0, 0);
  stage(1, 1);
#pragma unroll
  for (int st = 0; st < 36; ++st) {
    if (st < 34) {
      asm volatile("s_waitcnt vmcnt(4)" ::: "memory");  // step st's 4 landed
    } else if (st == 34) {
      asm volatile("s_waitcnt vmcnt(4)" ::: "memory");  // only 35's remain
    } else {
      asm volatile("s_waitcnt vmcnt(0)" ::: "memory");
    }
    __builtin_amdgcn_s_barrier();     // all waves' step-st loads landed;
    asm volatile("" ::: "memory");    // all waves' step-(st-1) reads done

    if (st < 34)
      stage(st + 2, (st + 2) % 3);    // overwrite buf read at st-1: safe

    int buf = st % 3;
    bf16x8 af[4], bfv[4];
#pragma unroll
    for (int mi = 0; mi < 4; ++mi)
      af[mi] = *(const bf16x8*)&As[buf][(wave_m + mi * 16 + l15) * 32 + koff];
#pragma unroll
    for (int ni = 0; ni < 4; ++ni)
      bfv[ni] = *(const bf16x8*)&Bs[buf][(wave_n + ni * 16 + l15) * 32 + koff];
#pragma unroll
    for (int mi = 0; mi < 4; ++mi)
#pragma unroll
      for (int ni = 0; ni < 4; ++ni)
        acc[mi][ni] = __builtin_amdgcn_mfma_f32_16x16x32_bf16(
            af[mi], bfv[ni], acc[mi][ni], 0, 0, 0);
  }

  // Epilogue: col(sp)=l15, row(co)=quad*4+reg; w'' = ni*16+l15, h_row = wid&1.
  int h_out = hh + (wid & 1);
#pragma unroll
  for (int mi = 0; mi < 4; ++mi) {
#pragma unroll
    for (int rg = 0; rg < 4; ++rg) {
      int co = co0 + wave_m + mi * 16 + quad * 4 + rg;
      float sv = s[co];
      float bv = bias[co];
      float* ob = out + (size_t)(n * C_OUT + co) * HW_SZ + h_out * W_SZ;
#pragma unroll
      for (int ni = 0; ni < 4; ++ni) {
        int wpp = ni * 16 + l15;      // 0..63 padded col
        if (wpp < W_SZ)
          ob[wpp] = acc[mi][ni][rg] * sv + bv;
      }
    }
  }
}

extern "C" void kernel_launch(void* const* d_in, const int* in_sizes, int n_in,
                              void* d_out, int out_size, void* d_ws, size_t ws_size,
                              hipStream_t stream) {
  const float* x    = (const float*)d_in[0];
  const int*   wq   = (const int*)d_in[1];
  const float* s    = (const float*)d_in[2];
  const float* bias = (const float*)d_in[3];
  float* out = (float*)d_out;

  char* ws = (char*)d_ws;
  ushort_t* wt = (ushort_t*)ws;                          // 589,824 B
  ushort_t* xp = (ushort_t*)(ws + 589824);               // (32*58+1)*16384 B ≈ 30.4 MB

  hipLaunchKernelGGL(wtrans_kernel, dim3((C_OUT * K_TOT) / 256), dim3(256), 0, stream,
                     wq, wt);
  hipLaunchKernelGGL(xpad_kernel, dim3(N_IMG * HP + 1), dim3(256), 0, stream, x, xp);
  hipLaunchKernelGGL(bitconv_kernel, dim3(1792), dim3(256), 0, stream,
                     wt, xp, s, bias, out);
}